// Round 6
// baseline (247.218 us; speedup 1.0000x reference)
//
#include <hip/hip_runtime.h>

#define B   8
#define C   256
#define N   4096
#define H   8
#define D   64
#define HID 512
#define SCALE 0.125f

typedef __attribute__((ext_vector_type(8))) __bf16 bf16x8;
typedef __attribute__((ext_vector_type(4))) float f32x4;

__device__ __forceinline__ ushort bfbits(float f) {
  union { __bf16 h; ushort u; } c; c.h = (__bf16)f; return c.u;
}

__device__ __forceinline__ f32x4 mfma16(bf16x8 a, bf16x8 b, f32x4 c) {
  return __builtin_amdgcn_mfma_f32_16x16x32_bf16(a, b, c, 0, 0, 0);
}

// global -> LDS direct DMA, 16 B per lane.  LDS dest is wave-uniform base
// (HW adds lane*16); global src is per-lane (pre-swizzled there).
__device__ __forceinline__ void glds16(const ushort* g, ushort* l) {
  __builtin_amdgcn_global_load_lds(
      (const __attribute__((address_space(1))) void*)g,
      (__attribute__((address_space(3))) void*)l, 16, 0, 0);
}

// ---------------------------------------------------------------------------
// Fused prep: z<8  -> transpose+cast ctxt[b] (fp32 [C][N] -> bf16 [N][C])
//             z<16 -> transpose+cast x[b-8]
//             z=16 -> cast Wk/Wv to bf16 (first 128 blocks of the plane)
// ---------------------------------------------------------------------------
__global__ __launch_bounds__(256) void prep_kernel(
    const float* __restrict__ x, const float* __restrict__ ctxt,
    const float* __restrict__ Wk, const float* __restrict__ Wv,
    ushort* __restrict__ x_bf, ushort* __restrict__ ctxt_bf,
    ushort* __restrict__ wk_bf, ushort* __restrict__ wv_bf) {
  const int z = blockIdx.z;
  const int tid = threadIdx.x;
  if (z == 16) {
    const int id = blockIdx.y * 64 + blockIdx.x;
    if (id >= 128) return;
    const int t = (id * 256 + tid) * 4;   // HID*C = 131072 elems
    const float4 a = *(const float4*)(Wk + t);
    const float4 b = *(const float4*)(Wv + t);
    ushort4 ra, rb;
    ra.x = bfbits(a.x); ra.y = bfbits(a.y); ra.z = bfbits(a.z); ra.w = bfbits(a.w);
    rb.x = bfbits(b.x); rb.y = bfbits(b.y); rb.z = bfbits(b.z); rb.w = bfbits(b.w);
    *(ushort4*)(wk_bf + t) = ra;
    *(ushort4*)(wv_bf + t) = rb;
    return;
  }
  __shared__ float tile[64 * 65];
  const int b = z & 7;
  const float* src = (z < 8) ? ctxt : x;
  ushort* dst = (z < 8) ? ctxt_bf : x_bf;
  const int l0 = blockIdx.x * 64, r0 = blockIdx.y * 64;
  const int rr = tid >> 4, c4 = (tid & 15) << 2;
  const float* sp = src + ((size_t)b * C + r0) * N + l0;
#pragma unroll
  for (int p = 0; p < 4; ++p) {
    const float4 v = *(const float4*)(sp + (size_t)(rr + p * 16) * N + c4);
    float* tp = tile + (rr + p * 16) * 65 + c4;
    tp[0] = v.x; tp[1] = v.y; tp[2] = v.z; tp[3] = v.w;
  }
  __syncthreads();
  const int lr = tid >> 2, rb = (tid & 3) << 4;
  uint pk[8];
#pragma unroll
  for (int k = 0; k < 16; k += 2) {
    const uint lo = bfbits(tile[(rb + k) * 65 + lr]);
    const uint hi = bfbits(tile[(rb + k + 1) * 65 + lr]);
    pk[k >> 1] = lo | (hi << 16);
  }
  ushort* dp = dst + ((size_t)b * N + l0 + lr) * C + r0 + rb;
  *(uint4*)dp = *(uint4*)pk;
  *(uint4*)(dp + 8) = *(uint4*)(pk + 4);
}

// ---------------------------------------------------------------------------
// Kernel 1 (MFMA): wave-per-d-slice, 32-m sub-tiles, glds double buffer,
// P/V double buffer, PV pipelined one sub-tile behind -> ONE barrier/tile.
// Per tile t: [issue glds t+1 -> cb[cur^1]] [proj t from cb[cur], weights
// loaded in-loop (L1-resident; hoisting spilled in R4/R5)] [exp + stage
// p/v[cur]] [PV t-1 from p/v[cur^1]] [__syncthreads].
// Hand-off proof: p/v[cur^1] written pre-prev-barrier; p/v[cur]'s last
// reader (PV t-1... at tile t-1) finished pre-prev-barrier; glds t+1 writes
// the cb buffer whose readers (proj t-1) finished pre-prev-barrier; the
// barrier's vmcnt(0) covers glds before proj t+1.  LDS 48 KB -> 3 blk/CU.
// ---------------------------------------------------------------------------
__global__ __launch_bounds__(256, 3) void kv_mfma_kernel(
    const ushort* __restrict__ ctxt_bf,   // [B][N][C] bf16
    const ushort* __restrict__ wk_bf,     // [HID][C]
    const ushort* __restrict__ wv_bf,
    float* __restrict__ ctx_part,         // [B*H][16][64*64]  ([d][e])
    float* __restrict__ z_part)           // [B*H][16][64]
{
  __shared__ __align__(16) ushort cb_s[2][32 * 256];  // 2 x 16 KB ctxt tiles
  __shared__ __align__(16) ushort p_s[2][64 * 32];    // 2 x 4 KB P ([d][m32])
  __shared__ __align__(16) ushort v_s[2][64 * 32];    // 2 x 4 KB V ([e][m32])
  const int mt = blockIdx.x, h = blockIdx.y, b = blockIdx.z;
  const int tid = threadIdx.x;
  const int w = tid >> 6, lane = tid & 63;
  const int col = lane & 15, quad = lane >> 4;
  const int dw = w * 16;
  const int swc = (col & 3) ^ ((col >> 2) & 3);   // P/V granule swizzle

  const ushort* wkp = wk_bf + (size_t)(h * 64 + dw + col) * C + quad * 8;
  const ushort* wvp = wv_bf + (size_t)(h * 64 + dw + col) * C + quad * 8;
  const ushort* cbase = ctxt_bf + ((size_t)b * N + (size_t)mt * 256) * C;

  const int grow0 = w * 8 + (lane >> 5);   // staging row (+ it*2)
  const int ggran = lane & 31;             // staging granule (16 B)

  const f32x4 z4 = {0.f, 0.f, 0.f, 0.f};
  f32x4 cacc[4];
#pragma unroll
  for (int j = 0; j < 4; ++j) cacc[j] = z4;
  float zl = 0.f;

  // prologue: stage sub-tile 0
#pragma unroll
  for (int it = 0; it < 4; ++it) {
    const int row = grow0 + it * 2;
    glds16(cbase + (size_t)row * C + ((ggran ^ (row & 7)) << 3),
           &cb_s[0][(w * 8 + it * 2) * 256]);
  }
  __syncthreads();

  for (int t = 0; t < 8; ++t) {
    const int cur = t & 1;
    // ---- issue prefetch for t+1 (drained at this tile's end barrier) ----
    if (t < 7) {
      const ushort* nb = cbase + (size_t)(t + 1) * 32 * C;
#pragma unroll
      for (int it = 0; it < 4; ++it) {
        const int row = grow0 + it * 2;
        glds16(nb + (size_t)row * C + ((ggran ^ (row & 7)) << 3),
               &cb_s[cur ^ 1][(w * 8 + it * 2) * 256]);
      }
    }

    // ---- K+V projection for own d-slice over 32 m (weights in-loop) ----
    f32x4 kacc[2], vacc[2];
#pragma unroll
    for (int i = 0; i < 2; ++i) { kacc[i] = z4; vacc[i] = z4; }
    __builtin_amdgcn_s_setprio(1);
#pragma unroll
    for (int kk = 0; kk < 8; ++kk) {
      bf16x8 a[2];
#pragma unroll
      for (int i = 0; i < 2; ++i) {
        const int r = i * 16 + col;
        a[i] = *(const bf16x8*)(&cb_s[cur][r * 256 +
                  ((((kk << 2) + quad) ^ (r & 7)) << 3)]);
      }
      const bf16x8 wkf = *(const bf16x8*)(wkp + (size_t)kk * 32);
      const bf16x8 wvf = *(const bf16x8*)(wvp + (size_t)kk * 32);
#pragma unroll
      for (int i = 0; i < 2; ++i) {
        kacc[i] = mfma16(a[i], wkf, kacc[i]);
        vacc[i] = mfma16(a[i], wvf, vacc[i]);
      }
    }
    __builtin_amdgcn_s_setprio(0);

    // ---- exp + stage P/V (own 16 d rows) into p/v[cur], Z partial ----
#pragma unroll
    for (int i = 0; i < 2; ++i) {
      const int off = (dw + col) * 32 +
                      (((i * 2 + (quad >> 1)) ^ swc) << 3) + ((quad & 1) << 2);
      const f32x4 k4 = kacc[i];
      const float e0 = __expf(k4[0]), e1 = __expf(k4[1]);
      const float e2 = __expf(k4[2]), e3 = __expf(k4[3]);
      zl += (e0 + e1) + (e2 + e3);
      ushort4 pk; pk.x = bfbits(e0); pk.y = bfbits(e1);
      pk.z = bfbits(e2); pk.w = bfbits(e3);
      *(ushort4*)(&p_s[cur][off]) = pk;
      const f32x4 v4 = vacc[i];
      ushort4 vk; vk.x = bfbits(v4[0]); vk.y = bfbits(v4[1]);
      vk.z = bfbits(v4[2]); vk.w = bfbits(v4[3]);
      *(ushort4*)(&v_s[cur][off]) = vk;
    }

    // ---- PV for sub-tile t-1 from p/v[cur^1] (staged last tile) ----
    if (t > 0) {
      const int g = (quad ^ swc) << 3;
      const bf16x8 pa = *(const bf16x8*)(&p_s[cur ^ 1][(dw + col) * 32 + g]);
      bf16x8 vb[4];
#pragma unroll
      for (int j = 0; j < 4; ++j)
        vb[j] = *(const bf16x8*)(&v_s[cur ^ 1][(j * 16 + col) * 32 + g]);
      __builtin_amdgcn_s_setprio(1);
#pragma unroll
      for (int j = 0; j < 4; ++j) cacc[j] = mfma16(pa, vb[j], cacc[j]);
      __builtin_amdgcn_s_setprio(0);
    }
    __syncthreads();   // drains glds (t+1) + makes p/v[cur] visible
  }

  // ---- epilogue PV: sub-tile 7 from p/v[1] ----
  {
    const int g = (quad ^ swc) << 3;
    const bf16x8 pa = *(const bf16x8*)(&p_s[1][(dw + col) * 32 + g]);
    bf16x8 vb[4];
#pragma unroll
    for (int j = 0; j < 4; ++j)
      vb[j] = *(const bf16x8*)(&v_s[1][(j * 16 + col) * 32 + g]);
#pragma unroll
    for (int j = 0; j < 4; ++j) cacc[j] = mfma16(pa, vb[j], cacc[j]);
  }

  // ---- Z: reduce over quads (wave owns its d-slice exclusively) ----
  {
    float s = zl;
    s += __shfl_xor(s, 16); s += __shfl_xor(s, 32);
    if (quad == 0)
      z_part[((size_t)(b * H + h) * 16 + mt) * 64 + dw + col] = s;
  }

  // ---- ctx epilogue: per-mt partials, [d][e] ----
  float* outp = ctx_part + ((size_t)(b * H + h) * 16 + mt) * 4096;
#pragma unroll
  for (int j = 0; j < 4; ++j)
#pragma unroll
    for (int r = 0; r < 4; ++r)
      outp[(size_t)(dw + quad * 4 + r) * 64 + j * 16 + col] = cacc[j][r];
}

// ---------------------------------------------------------------------------
// Kernel 2: sum partials, normalize by Z (per d = idx>>6), fold in scale.
// ctx_part / ctxn are [d][e].  Grid (B*H, 16).
// ---------------------------------------------------------------------------
__global__ __launch_bounds__(256) void combine_kernel(
    const float* __restrict__ ctx_part, const float* __restrict__ z_part,
    float* __restrict__ ctxn)            // [B*H][64(d)][64(e)]
{
  const int bh = blockIdx.x, seg = blockIdx.y, tid = threadIdx.x;
  __shared__ float zs[64];
  if (tid < 64) {
    float z = 0.f;
#pragma unroll
    for (int p = 0; p < 16; ++p) z += z_part[((size_t)bh * 16 + p) * 64 + tid];
    zs[tid] = SCALE / z;
  }
  __syncthreads();
  const int idx = (seg << 8) + tid;
  const float* cp = ctx_part + (size_t)bh * 16 * 4096;
  float s = 0.f;
#pragma unroll
  for (int p = 0; p < 16; ++p) s += cp[(size_t)p * 4096 + idx];
  ctxn[((size_t)bh << 12) + idx] = s * zs[idx >> 6];
}

// ---------------------------------------------------------------------------
// Kernel 3a: A[b][h*64+e][c] = sum_d ctxn[b,h][d][e] * Wq[h*64+d, c]   (fp32)
// Grid (B*H, 4): one 64-col c-tile per block.  ctxn [d][e] -> ct[e][d].
// ---------------------------------------------------------------------------
__global__ __launch_bounds__(256) void a_kernel(
    const float* __restrict__ ctxn, const float* __restrict__ Wq,
    float* __restrict__ A)               // [B][HID][C]
{
  const int bh = blockIdx.x, cti = blockIdx.y, tid = threadIdx.x;
  const int b = bh >> 3, h = bh & 7;
  const int c0 = cti << 6;
  __shared__ float ct[64 * 65];   // [e][d]
  __shared__ float wq[64 * 68];   // [d][c-tile]
  for (int r = 0; r < 16; ++r) {
    const int idx = tid + (r << 8);
    ct[(idx & 63) * 65 + (idx >> 6)] = ctxn[((size_t)bh << 12) + idx];
    wq[(idx >> 6) * 68 + (idx & 63)] =
        Wq[(size_t)(h * 64 + (idx >> 6)) * C + c0 + (idx & 63)];
  }
  __syncthreads();
  const int e = tid & 63, co = tid >> 6;
  float acc[16];
#pragma unroll
  for (int k = 0; k < 16; ++k) acc[k] = 0.f;
  for (int d = 0; d < 64; ++d) {
    const float cv = ct[e * 65 + d];
    const float* wr = wq + d * 68 + co * 16;
#pragma unroll
    for (int k = 0; k < 16; ++k) acc[k] += cv * wr[k];
  }
  float* Ar = A + ((size_t)b * HID + h * 64 + e) * C + c0 + co * 16;
#pragma unroll
  for (int k = 0; k < 16; ++k) Ar[k] = acc[k];
}

// ---------------------------------------------------------------------------
// Kernel 3b: M[b] = Wo (256x512) @ A[b] (512x256) -> bf16 [b][o][c]
// 32x64 tiles, grid (32, B).  k-chunk 64, reg-staged write-late pipeline.
// ---------------------------------------------------------------------------
__global__ __launch_bounds__(256) void m_kernel(
    const float* __restrict__ A, const float* __restrict__ Wo,
    ushort* __restrict__ M_bf)
{
  const int tile = blockIdx.x, b = blockIdx.y;
  const int o0 = (tile & 7) << 5, c0 = (tile >> 3) << 6;
  const int tid = threadIdx.x, tx = tid & 15, ty = tid >> 4;
  __shared__ float wo_s[64 * 33];  // [k][o 32]
  __shared__ float a_s[64 * 68];   // [k][c 64]
  float acc[2][4] = {{0.f}};
  const int wo_o = tid >> 3, wo_k = (tid & 7) << 3;   // 8 k per thread
  const int a_k = tid >> 2, a_c = (tid & 3) << 4;     // 16 c per thread
  float4 wr0, wr1, ar0, ar1, ar2, ar3;
  {
    const float* wp = Wo + (size_t)(o0 + wo_o) * HID + wo_k;
    wr0 = *(const float4*)wp; wr1 = *(const float4*)(wp + 4);
    const float* ap = A + ((size_t)b * HID + a_k) * C + c0 + a_c;
    ar0 = *(const float4*)ap;       ar1 = *(const float4*)(ap + 4);
    ar2 = *(const float4*)(ap + 8); ar3 = *(const float4*)(ap + 12);
  }
  for (int t = 0; t < 8; ++t) {
    __syncthreads();   // previous compute done reading LDS
    {
      float* wd = wo_s + wo_k * 33 + wo_o;
      wd[0]   = wr0.x; wd[33]  = wr0.y; wd[66]  = wr0.z; wd[99]  = wr0.w;
      wd[132] = wr1.x; wd[165] = wr1.y; wd[198] = wr1.z; wd[231] = wr1.w;
      float* ad = a_s + a_k * 68 + a_c;
      *(float4*)ad = ar0;       *(float4*)(ad + 4) = ar1;
      *(float4*)(ad + 8) = ar2; *(float4*)(ad + 12) = ar3;
    }
    __syncthreads();
    if (t < 7) {
      const int k0 = (t + 1) << 6;
      const float* wp = Wo + (size_t)(o0 + wo_o) * HID + k0 + wo_k;
      wr0 = *(const float4*)wp; wr1 = *(const float4*)(wp + 4);
      const float* ap = A + ((size_t)b * HID + k0 + a_k) * C + c0 + a_c;
      ar0 = *(const float4*)ap;       ar1 = *(const float4*)(ap + 4);
      ar2 = *(const float4*)(ap + 8); ar3 = *(const float4*)(ap + 12);
    }
#pragma unroll
    for (int kc = 0; kc < 64; ++kc) {
      const float2 wv = *(const float2*)(wo_s + kc * 33 + ty * 2);
      const float4 av = *(const float4*)(a_s + kc * 68 + tx * 4);
      acc[0][0] += wv.x * av.x; acc[0][1] += wv.x * av.y;
      acc[0][2] += wv.x * av.z; acc[0][3] += wv.x * av.w;
      acc[1][0] += wv.y * av.x; acc[1][1] += wv.y * av.y;
      acc[1][2] += wv.y * av.z; acc[1][3] += wv.y * av.w;
    }
  }
#pragma unroll
  for (int i = 0; i < 2; ++i) {
    ushort4 r;
    r.x = bfbits(acc[i][0]); r.y = bfbits(acc[i][1]);
    r.z = bfbits(acc[i][2]); r.w = bfbits(acc[i][3]);
    *(ushort4*)(M_bf + ((size_t)b * C + o0 + ty * 2 + i) * C + c0 + tx * 4) = r;
  }
}

// ---------------------------------------------------------------------------
// Kernel 4 (MFMA): out[b] = M_b (256x256) @ X_b (256x4096) + bo
// Block->XCD remap: the 8 ot-blocks sharing one 128 KB x-tile get the same
// XCD and adjacent slots, so the x-tile stays in that XCD's L2.
// ---------------------------------------------------------------------------
__global__ __launch_bounds__(256, 4) void out_mfma_kernel(
    const ushort* __restrict__ M_bf,     // [B][C][C] bf16
    const ushort* __restrict__ x_bf,     // [B][N][C] bf16
    const float* __restrict__ bo, float* __restrict__ out)
{
  const int r = blockIdx.x + 16 * blockIdx.y + 128 * blockIdx.z;  // 0..1023
  const int xcd = r & 7, slot = r >> 3;
  const int grp = xcd * 16 + (slot >> 3);   // 0..127 = (b, nt)
  const int ot = slot & 7;
  const int b = grp >> 4, nt = grp & 15;
  const int tid = threadIdx.x;
  const int w = tid >> 6, lane = tid & 63;
  const int col = lane & 15, quad = lane >> 4;
  const int o0 = ot * 32;
  const size_t n_base = (size_t)nt * 256 + w * 64;
  const ushort* Ab = M_bf + ((size_t)b * C + o0 + col) * C + quad * 8;
  const ushort* Bb = x_bf + ((size_t)b * N + n_base) * C + quad * 8;

  const f32x4 z4 = {0.f, 0.f, 0.f, 0.f};
  f32x4 acc[2][4];
#pragma unroll
  for (int i = 0; i < 2; ++i)
#pragma unroll
    for (int j = 0; j < 4; ++j) acc[i][j] = z4;

#pragma unroll
  for (int kk = 0; kk < 8; ++kk) {
    bf16x8 af[2], bfz[4];
#pragma unroll
    for (int i = 0; i < 2; ++i)
      af[i] = *(const bf16x8*)(Ab + (size_t)(i * 16) * C + kk * 32);
#pragma unroll
    for (int j = 0; j < 4; ++j)
      bfz[j] = *(const bf16x8*)(Bb + (size_t)(j * 16 + col) * C + kk * 32);
#pragma unroll
    for (int i = 0; i < 2; ++i)
#pragma unroll
      for (int j = 0; j < 4; ++j) acc[i][j] = mfma16(af[i], bfz[j], acc[i][j]);
  }

#pragma unroll
  for (int i = 0; i < 2; ++i)
#pragma unroll
    for (int r2 = 0; r2 < 4; ++r2) {
      const int o = o0 + i * 16 + quad * 4 + r2;
      const float bias = bo[o];
      float* op = out + ((size_t)b * C + o) * N + n_base + col;
#pragma unroll
      for (int j = 0; j < 4; ++j) op[j * 16] = acc[i][j][r2] + bias;
    }
}

// ---------------------------------------------------------------------------
extern "C" void kernel_launch(void* const* d_in, const int* in_sizes, int n_in,
                              void* d_out, int out_size, void* d_ws, size_t ws_size,
                              hipStream_t stream) {
  const float* x    = (const float*)d_in[0];
  const float* ctxt = (const float*)d_in[1];
  const float* Wq   = (const float*)d_in[2];
  const float* Wk   = (const float*)d_in[3];
  const float* Wv   = (const float*)d_in[4];
  const float* Wo   = (const float*)d_in[5];
  const float* bo   = (const float*)d_in[6];
  float* out = (float*)d_out;

  char* p = (char*)d_ws;
  ushort* ctxt_bf = (ushort*)p;  p += (size_t)B * N * C * 2;        // 16 MB
  ushort* x_bf    = (ushort*)p;  p += (size_t)B * N * C * 2;        // 16 MB
  ushort* wk_bf   = (ushort*)p;  p += (size_t)HID * C * 2;
  ushort* wv_bf   = (ushort*)p;  p += (size_t)HID * C * 2;
  ushort* M_bf    = (ushort*)p;  p += (size_t)B * C * C * 2;
  float*  z_part  = (float*)p;   p += (size_t)B * H * 16 * 64 * 4;
  float*  ctxn    = (float*)p;   p += (size_t)B * H * D * D * 4;
  float*  ctx_part= (float*)p;   p += (size_t)B * H * 16 * 4096 * 4; // 16.8 MB
  float*  A       = ctx_part;    // aliased: ctx_part dead after combine_kernel

  prep_kernel<<<dim3(N / 64, C / 64, 17), 256, 0, stream>>>(
      x, ctxt, Wk, Wv, x_bf, ctxt_bf, wk_bf, wv_bf);
  kv_mfma_kernel<<<dim3(16, H, B), 256, 0, stream>>>(
      ctxt_bf, wk_bf, wv_bf, ctx_part, z_part);
  combine_kernel<<<dim3(B * H, 16), 256, 0, stream>>>(ctx_part, z_part, ctxn);
  a_kernel<<<dim3(B * H, 4), 256, 0, stream>>>(ctxn, Wq, A);
  m_kernel<<<dim3(32, B), 256, 0, stream>>>(A, Wo, M_bf);
  out_mfma_kernel<<<dim3(N / 256, C / 32, B), 256, 0, stream>>>(M_bf, x_bf, bo, out);
}

// Round 7
// 232.130 us; speedup vs baseline: 1.0650x; 1.0650x over previous
//
#include <hip/hip_runtime.h>

#define B   8
#define C   256
#define N   4096
#define H   8
#define D   64
#define HID 512
#define SCALE 0.125f

typedef __attribute__((ext_vector_type(8))) __bf16 bf16x8;
typedef __attribute__((ext_vector_type(4))) float f32x4;

__device__ __forceinline__ ushort bfbits(float f) {
  union { __bf16 h; ushort u; } c; c.h = (__bf16)f; return c.u;
}

__device__ __forceinline__ f32x4 mfma16(bf16x8 a, bf16x8 b, f32x4 c) {
  return __builtin_amdgcn_mfma_f32_16x16x32_bf16(a, b, c, 0, 0, 0);
}

// global -> LDS direct DMA, 16 B per lane.  LDS dest is wave-uniform base
// (HW adds lane*16); global src is per-lane (pre-swizzled there).
__device__ __forceinline__ void glds16(const ushort* g, ushort* l) {
  __builtin_amdgcn_global_load_lds(
      (const __attribute__((address_space(1))) void*)g,
      (__attribute__((address_space(3))) void*)l, 16, 0, 0);
}

// ---------------------------------------------------------------------------
// Fused prep: z<8  -> transpose+cast ctxt[b] (fp32 [C][N] -> bf16 [N][C])
//             z<16 -> transpose+cast x[b-8]
//             z=16 -> cast Wk/Wv to bf16 (first 128 blocks of the plane)
// ---------------------------------------------------------------------------
__global__ __launch_bounds__(256) void prep_kernel(
    const float* __restrict__ x, const float* __restrict__ ctxt,
    const float* __restrict__ Wk, const float* __restrict__ Wv,
    ushort* __restrict__ x_bf, ushort* __restrict__ ctxt_bf,
    ushort* __restrict__ wk_bf, ushort* __restrict__ wv_bf) {
  const int z = blockIdx.z;
  const int tid = threadIdx.x;
  if (z == 16) {
    const int id = blockIdx.y * 64 + blockIdx.x;
    if (id >= 128) return;
    const int t = (id * 256 + tid) * 4;   // HID*C = 131072 elems
    const float4 a = *(const float4*)(Wk + t);
    const float4 b = *(const float4*)(Wv + t);
    ushort4 ra, rb;
    ra.x = bfbits(a.x); ra.y = bfbits(a.y); ra.z = bfbits(a.z); ra.w = bfbits(a.w);
    rb.x = bfbits(b.x); rb.y = bfbits(b.y); rb.z = bfbits(b.z); rb.w = bfbits(b.w);
    *(ushort4*)(wk_bf + t) = ra;
    *(ushort4*)(wv_bf + t) = rb;
    return;
  }
  __shared__ float tile[64 * 65];
  const int b = z & 7;
  const float* src = (z < 8) ? ctxt : x;
  ushort* dst = (z < 8) ? ctxt_bf : x_bf;
  const int l0 = blockIdx.x * 64, r0 = blockIdx.y * 64;
  const int rr = tid >> 4, c4 = (tid & 15) << 2;
  const float* sp = src + ((size_t)b * C + r0) * N + l0;
#pragma unroll
  for (int p = 0; p < 4; ++p) {
    const float4 v = *(const float4*)(sp + (size_t)(rr + p * 16) * N + c4);
    float* tp = tile + (rr + p * 16) * 65 + c4;
    tp[0] = v.x; tp[1] = v.y; tp[2] = v.z; tp[3] = v.w;
  }
  __syncthreads();
  const int lr = tid >> 2, rb = (tid & 3) << 4;
  uint pk[8];
#pragma unroll
  for (int k = 0; k < 16; k += 2) {
    const uint lo = bfbits(tile[(rb + k) * 65 + lr]);
    const uint hi = bfbits(tile[(rb + k + 1) * 65 + lr]);
    pk[k >> 1] = lo | (hi << 16);
  }
  ushort* dp = dst + ((size_t)b * N + l0 + lr) * C + r0 + rb;
  *(uint4*)dp = *(uint4*)pk;
  *(uint4*)(dp + 8) = *(uint4*)(pk + 4);
}

// ---------------------------------------------------------------------------
// Kernel 1 (MFMA) -- exact R3 structure (best measured: 40.8 us).
// Wave-per-d-slice, 32-m sub-tiles, glds double buffer for ctxt staging,
// single P/V buffer, 2 barriers/tile, in-loop weight loads (L1-resident),
// NO setprio (R6 showed it + pipelined-PV cost 2x).  LDS 40 KB -> 4 blk/CU.
// ---------------------------------------------------------------------------
__global__ __launch_bounds__(256, 4) void kv_mfma_kernel(
    const ushort* __restrict__ ctxt_bf,   // [B][N][C] bf16
    const ushort* __restrict__ wk_bf,     // [HID][C]
    const ushort* __restrict__ wv_bf,
    float* __restrict__ ctx_part,         // [B*H][16][64*64]  ([d][e])
    float* __restrict__ z_part)           // [B*H][16][64]
{
  __shared__ __align__(16) ushort cb_s[2][32 * 256];  // 2 x 16 KB ctxt tiles
  __shared__ __align__(16) ushort p_s[64 * 32];       // 4 KB P ([d][m32])
  __shared__ __align__(16) ushort v_s[64 * 32];       // 4 KB V ([e][m32])
  const int mt = blockIdx.x, h = blockIdx.y, b = blockIdx.z;
  const int tid = threadIdx.x;
  const int w = tid >> 6, lane = tid & 63;
  const int col = lane & 15, quad = lane >> 4;
  const int dw = w * 16;
  const int swc = (col & 3) ^ ((col >> 2) & 3);   // P/V granule swizzle

  const ushort* wkp = wk_bf + (size_t)(h * 64 + dw + col) * C + quad * 8;
  const ushort* wvp = wv_bf + (size_t)(h * 64 + dw + col) * C + quad * 8;
  const ushort* cbase = ctxt_bf + ((size_t)b * N + (size_t)mt * 256) * C;

  const int grow0 = w * 8 + (lane >> 5);   // staging row (+ it*2)
  const int ggran = lane & 31;             // staging granule (16 B)

  const f32x4 z4 = {0.f, 0.f, 0.f, 0.f};
  f32x4 cacc[4];
#pragma unroll
  for (int j = 0; j < 4; ++j) cacc[j] = z4;
  float zl = 0.f;

  // prologue: stage sub-tile 0
#pragma unroll
  for (int it = 0; it < 4; ++it) {
    const int row = grow0 + it * 2;
    glds16(cbase + (size_t)row * C + ((ggran ^ (row & 7)) << 3),
           &cb_s[0][(w * 8 + it * 2) * 256]);
  }
  __syncthreads();

  for (int t = 0; t < 8; ++t) {
    const int cur = t & 1;
    if (t < 7) {
      const ushort* nb = cbase + (size_t)(t + 1) * 32 * C;
#pragma unroll
      for (int it = 0; it < 4; ++it) {
        const int row = grow0 + it * 2;
        glds16(nb + (size_t)row * C + ((ggran ^ (row & 7)) << 3),
               &cb_s[cur ^ 1][(w * 8 + it * 2) * 256]);
      }
    }

    // ---- K+V projection for own d-slice over 32 m (weights in-loop) ----
    f32x4 kacc[2], vacc[2];
#pragma unroll
    for (int i = 0; i < 2; ++i) { kacc[i] = z4; vacc[i] = z4; }
#pragma unroll
    for (int kk = 0; kk < 8; ++kk) {
      bf16x8 a[2];
#pragma unroll
      for (int i = 0; i < 2; ++i) {
        const int r = i * 16 + col;
        a[i] = *(const bf16x8*)(&cb_s[cur][r * 256 +
                  ((((kk << 2) + quad) ^ (r & 7)) << 3)]);
      }
      const bf16x8 wkf = *(const bf16x8*)(wkp + (size_t)kk * 32);
      const bf16x8 wvf = *(const bf16x8*)(wvp + (size_t)kk * 32);
#pragma unroll
      for (int i = 0; i < 2; ++i) {
        kacc[i] = mfma16(a[i], wkf, kacc[i]);
        vacc[i] = mfma16(a[i], wvf, vacc[i]);
      }
    }

    // ---- exp + stage P/V (own 16 d rows), Z partial ----
#pragma unroll
    for (int i = 0; i < 2; ++i) {
      const int off = (dw + col) * 32 +
                      (((i * 2 + (quad >> 1)) ^ swc) << 3) + ((quad & 1) << 2);
      const f32x4 k4 = kacc[i];
      const float e0 = __expf(k4[0]), e1 = __expf(k4[1]);
      const float e2 = __expf(k4[2]), e3 = __expf(k4[3]);
      zl += (e0 + e1) + (e2 + e3);
      ushort4 pk; pk.x = bfbits(e0); pk.y = bfbits(e1);
      pk.z = bfbits(e2); pk.w = bfbits(e3);
      *(ushort4*)(p_s + off) = pk;
      const f32x4 v4 = vacc[i];
      ushort4 vk; vk.x = bfbits(v4[0]); vk.y = bfbits(v4[1]);
      vk.z = bfbits(v4[2]); vk.w = bfbits(v4[3]);
      *(ushort4*)(v_s + off) = vk;
    }
    __syncthreads();

    // ---- PV accumulate: one K-step over this sub-tile's 32 m ----
    {
      const int g = (quad ^ swc) << 3;
      const bf16x8 pa = *(const bf16x8*)(p_s + (dw + col) * 32 + g);
      bf16x8 vb[4];
#pragma unroll
      for (int j = 0; j < 4; ++j)
        vb[j] = *(const bf16x8*)(v_s + (j * 16 + col) * 32 + g);
#pragma unroll
      for (int j = 0; j < 4; ++j) cacc[j] = mfma16(pa, vb[j], cacc[j]);
    }
    __syncthreads();   // P/V reuse + cb prefetch completion
  }

  // ---- Z: reduce over quads (wave owns its d-slice exclusively) ----
  {
    float s = zl;
    s += __shfl_xor(s, 16); s += __shfl_xor(s, 32);
    if (quad == 0)
      z_part[((size_t)(b * H + h) * 16 + mt) * 64 + dw + col] = s;
  }

  // ---- ctx epilogue: per-mt partials, [d][e] ----
  float* outp = ctx_part + ((size_t)(b * H + h) * 16 + mt) * 4096;
#pragma unroll
  for (int j = 0; j < 4; ++j)
#pragma unroll
    for (int r = 0; r < 4; ++r)
      outp[(size_t)(dw + quad * 4 + r) * 64 + j * 16 + col] = cacc[j][r];
}

// ---------------------------------------------------------------------------
// Kernel 2: sum partials, normalize by Z (per d = idx>>6), fold in scale.
// ctx_part / ctxn are [d][e].  Grid (B*H, 16).
// ---------------------------------------------------------------------------
__global__ __launch_bounds__(256) void combine_kernel(
    const float* __restrict__ ctx_part, const float* __restrict__ z_part,
    float* __restrict__ ctxn)            // [B*H][64(d)][64(e)]
{
  const int bh = blockIdx.x, seg = blockIdx.y, tid = threadIdx.x;
  __shared__ float zs[64];
  if (tid < 64) {
    float z = 0.f;
#pragma unroll
    for (int p = 0; p < 16; ++p) z += z_part[((size_t)bh * 16 + p) * 64 + tid];
    zs[tid] = SCALE / z;
  }
  __syncthreads();
  const int idx = (seg << 8) + tid;
  const float* cp = ctx_part + (size_t)bh * 16 * 4096;
  float s = 0.f;
#pragma unroll
  for (int p = 0; p < 16; ++p) s += cp[(size_t)p * 4096 + idx];
  ctxn[((size_t)bh << 12) + idx] = s * zs[idx >> 6];
}

// ---------------------------------------------------------------------------
// Kernel 3a: A[b][h*64+e][c] = sum_d ctxn[b,h][d][e] * Wq[h*64+d, c]   (fp32)
// Grid (B*H, 4): one 64-col c-tile per block.  ctxn [d][e] -> ct[e][d].
// ---------------------------------------------------------------------------
__global__ __launch_bounds__(256) void a_kernel(
    const float* __restrict__ ctxn, const float* __restrict__ Wq,
    float* __restrict__ A)               // [B][HID][C]
{
  const int bh = blockIdx.x, cti = blockIdx.y, tid = threadIdx.x;
  const int b = bh >> 3, h = bh & 7;
  const int c0 = cti << 6;
  __shared__ float ct[64 * 65];   // [e][d]
  __shared__ float wq[64 * 68];   // [d][c-tile]
  for (int r = 0; r < 16; ++r) {
    const int idx = tid + (r << 8);
    ct[(idx & 63) * 65 + (idx >> 6)] = ctxn[((size_t)bh << 12) + idx];
    wq[(idx >> 6) * 68 + (idx & 63)] =
        Wq[(size_t)(h * 64 + (idx >> 6)) * C + c0 + (idx & 63)];
  }
  __syncthreads();
  const int e = tid & 63, co = tid >> 6;
  float acc[16];
#pragma unroll
  for (int k = 0; k < 16; ++k) acc[k] = 0.f;
  for (int d = 0; d < 64; ++d) {
    const float cv = ct[e * 65 + d];
    const float* wr = wq + d * 68 + co * 16;
#pragma unroll
    for (int k = 0; k < 16; ++k) acc[k] += cv * wr[k];
  }
  float* Ar = A + ((size_t)b * HID + h * 64 + e) * C + c0 + co * 16;
#pragma unroll
  for (int k = 0; k < 16; ++k) Ar[k] = acc[k];
}

// ---------------------------------------------------------------------------
// Kernel 3b: M[b] = Wo (256x512) @ A[b] (512x256) -> bf16 [b][o][c]
// 32x64 tiles, grid (32, B).  k-chunk 64, reg-staged write-late pipeline.
// ---------------------------------------------------------------------------
__global__ __launch_bounds__(256) void m_kernel(
    const float* __restrict__ A, const float* __restrict__ Wo,
    ushort* __restrict__ M_bf)
{
  const int tile = blockIdx.x, b = blockIdx.y;
  const int o0 = (tile & 7) << 5, c0 = (tile >> 3) << 6;
  const int tid = threadIdx.x, tx = tid & 15, ty = tid >> 4;
  __shared__ float wo_s[64 * 33];  // [k][o 32]
  __shared__ float a_s[64 * 68];   // [k][c 64]
  float acc[2][4] = {{0.f}};
  const int wo_o = tid >> 3, wo_k = (tid & 7) << 3;   // 8 k per thread
  const int a_k = tid >> 2, a_c = (tid & 3) << 4;     // 16 c per thread
  float4 wr0, wr1, ar0, ar1, ar2, ar3;
  {
    const float* wp = Wo + (size_t)(o0 + wo_o) * HID + wo_k;
    wr0 = *(const float4*)wp; wr1 = *(const float4*)(wp + 4);
    const float* ap = A + ((size_t)b * HID + a_k) * C + c0 + a_c;
    ar0 = *(const float4*)ap;       ar1 = *(const float4*)(ap + 4);
    ar2 = *(const float4*)(ap + 8); ar3 = *(const float4*)(ap + 12);
  }
  for (int t = 0; t < 8; ++t) {
    __syncthreads();   // previous compute done reading LDS
    {
      float* wd = wo_s + wo_k * 33 + wo_o;
      wd[0]   = wr0.x; wd[33]  = wr0.y; wd[66]  = wr0.z; wd[99]  = wr0.w;
      wd[132] = wr1.x; wd[165] = wr1.y; wd[198] = wr1.z; wd[231] = wr1.w;
      float* ad = a_s + a_k * 68 + a_c;
      *(float4*)ad = ar0;       *(float4*)(ad + 4) = ar1;
      *(float4*)(ad + 8) = ar2; *(float4*)(ad + 12) = ar3;
    }
    __syncthreads();
    if (t < 7) {
      const int k0 = (t + 1) << 6;
      const float* wp = Wo + (size_t)(o0 + wo_o) * HID + k0 + wo_k;
      wr0 = *(const float4*)wp; wr1 = *(const float4*)(wp + 4);
      const float* ap = A + ((size_t)b * HID + k0 + a_k) * C + c0 + a_c;
      ar0 = *(const float4*)ap;       ar1 = *(const float4*)(ap + 4);
      ar2 = *(const float4*)(ap + 8); ar3 = *(const float4*)(ap + 12);
    }
#pragma unroll
    for (int kc = 0; kc < 64; ++kc) {
      const float2 wv = *(const float2*)(wo_s + kc * 33 + ty * 2);
      const float4 av = *(const float4*)(a_s + kc * 68 + tx * 4);
      acc[0][0] += wv.x * av.x; acc[0][1] += wv.x * av.y;
      acc[0][2] += wv.x * av.z; acc[0][3] += wv.x * av.w;
      acc[1][0] += wv.y * av.x; acc[1][1] += wv.y * av.y;
      acc[1][2] += wv.y * av.z; acc[1][3] += wv.y * av.w;
    }
  }
#pragma unroll
  for (int i = 0; i < 2; ++i) {
    ushort4 r;
    r.x = bfbits(acc[i][0]); r.y = bfbits(acc[i][1]);
    r.z = bfbits(acc[i][2]); r.w = bfbits(acc[i][3]);
    *(ushort4*)(M_bf + ((size_t)b * C + o0 + ty * 2 + i) * C + c0 + tx * 4) = r;
  }
}

// ---------------------------------------------------------------------------
// Kernel 4 (MFMA): out[b] = M_b (256x256) @ X_b (256x4096) + bo
// Block->XCD remap: the 8 ot-blocks sharing one 128 KB x-tile get the same
// XCD and adjacent slots, so the x-tile stays in that XCD's L2.
// ---------------------------------------------------------------------------
__global__ __launch_bounds__(256, 4) void out_mfma_kernel(
    const ushort* __restrict__ M_bf,     // [B][C][C] bf16
    const ushort* __restrict__ x_bf,     // [B][N][C] bf16
    const float* __restrict__ bo, float* __restrict__ out)
{
  const int r = blockIdx.x + 16 * blockIdx.y + 128 * blockIdx.z;  // 0..1023
  const int xcd = r & 7, slot = r >> 3;
  const int grp = xcd * 16 + (slot >> 3);   // 0..127 = (b, nt)
  const int ot = slot & 7;
  const int b = grp >> 4, nt = grp & 15;
  const int tid = threadIdx.x;
  const int w = tid >> 6, lane = tid & 63;
  const int col = lane & 15, quad = lane >> 4;
  const int o0 = ot * 32;
  const size_t n_base = (size_t)nt * 256 + w * 64;
  const ushort* Ab = M_bf + ((size_t)b * C + o0 + col) * C + quad * 8;
  const ushort* Bb = x_bf + ((size_t)b * N + n_base) * C + quad * 8;

  const f32x4 z4 = {0.f, 0.f, 0.f, 0.f};
  f32x4 acc[2][4];
#pragma unroll
  for (int i = 0; i < 2; ++i)
#pragma unroll
    for (int j = 0; j < 4; ++j) acc[i][j] = z4;

#pragma unroll
  for (int kk = 0; kk < 8; ++kk) {
    bf16x8 af[2], bfz[4];
#pragma unroll
    for (int i = 0; i < 2; ++i)
      af[i] = *(const bf16x8*)(Ab + (size_t)(i * 16) * C + kk * 32);
#pragma unroll
    for (int j = 0; j < 4; ++j)
      bfz[j] = *(const bf16x8*)(Bb + (size_t)(j * 16 + col) * C + kk * 32);
#pragma unroll
    for (int i = 0; i < 2; ++i)
#pragma unroll
      for (int j = 0; j < 4; ++j) acc[i][j] = mfma16(af[i], bfz[j], acc[i][j]);
  }

#pragma unroll
  for (int i = 0; i < 2; ++i)
#pragma unroll
    for (int r2 = 0; r2 < 4; ++r2) {
      const int o = o0 + i * 16 + quad * 4 + r2;
      const float bias = bo[o];
      float* op = out + ((size_t)b * C + o) * N + n_base + col;
#pragma unroll
      for (int j = 0; j < 4; ++j) op[j * 16] = acc[i][j][r2] + bias;
    }
}

// ---------------------------------------------------------------------------
extern "C" void kernel_launch(void* const* d_in, const int* in_sizes, int n_in,
                              void* d_out, int out_size, void* d_ws, size_t ws_size,
                              hipStream_t stream) {
  const float* x    = (const float*)d_in[0];
  const float* ctxt = (const float*)d_in[1];
  const float* Wq   = (const float*)d_in[2];
  const float* Wk   = (const float*)d_in[3];
  const float* Wv   = (const float*)d_in[4];
  const float* Wo   = (const float*)d_in[5];
  const float* bo   = (const float*)d_in[6];
  float* out = (float*)d_out;

  char* p = (char*)d_ws;
  ushort* ctxt_bf = (ushort*)p;  p += (size_t)B * N * C * 2;        // 16 MB
  ushort* x_bf    = (ushort*)p;  p += (size_t)B * N * C * 2;        // 16 MB
  ushort* wk_bf   = (ushort*)p;  p += (size_t)HID * C * 2;
  ushort* wv_bf   = (ushort*)p;  p += (size_t)HID * C * 2;
  ushort* M_bf    = (ushort*)p;  p += (size_t)B * C * C * 2;
  float*  z_part  = (float*)p;   p += (size_t)B * H * 16 * 64 * 4;
  float*  ctxn    = (float*)p;   p += (size_t)B * H * D * D * 4;
  float*  ctx_part= (float*)p;   p += (size_t)B * H * 16 * 4096 * 4; // 16.8 MB
  float*  A       = ctx_part;    // aliased: ctx_part dead after combine_kernel

  prep_kernel<<<dim3(N / 64, C / 64, 17), 256, 0, stream>>>(
      x, ctxt, Wk, Wv, x_bf, ctxt_bf, wk_bf, wv_bf);
  kv_mfma_kernel<<<dim3(16, H, B), 256, 0, stream>>>(
      ctxt_bf, wk_bf, wv_bf, ctx_part, z_part);
  combine_kernel<<<dim3(B * H, 16), 256, 0, stream>>>(ctx_part, z_part, ctxn);
  a_kernel<<<dim3(B * H, 4), 256, 0, stream>>>(ctxn, Wq, A);
  m_kernel<<<dim3(32, B), 256, 0, stream>>>(A, Wo, M_bf);
  out_mfma_kernel<<<dim3(N / 256, C / 32, B), 256, 0, stream>>>(M_bf, x_bf, bo, out);
}

// Round 8
// 202.138 us; speedup vs baseline: 1.2230x; 1.1484x over previous
//
#include <hip/hip_runtime.h>

#define B   8
#define C   256
#define N   4096
#define H   8
#define D   64
#define HID 512
#define SCALE 0.125f

typedef __attribute__((ext_vector_type(8))) __bf16 bf16x8;
typedef __attribute__((ext_vector_type(4))) float f32x4;

// Software RNE fp32->bf16.  Bit-identical to v_cvt for normals, but the
// integer sequence keeps kv's register allocation at 64 VGPR -- the hw-cast
// variant (R7) dropped it to 52 and the shrunken ILP window cost 1.7x.
__device__ __forceinline__ ushort f2bf(float f) {
  union { float f; unsigned u; } v; v.f = f;
  unsigned r = v.u + 0x7FFFu + ((v.u >> 16) & 1u);
  return (ushort)(r >> 16);
}

__device__ __forceinline__ f32x4 mfma16(bf16x8 a, bf16x8 b, f32x4 c) {
  return __builtin_amdgcn_mfma_f32_16x16x32_bf16(a, b, c, 0, 0, 0);
}

// global -> LDS direct DMA, 16 B per lane.  LDS dest is wave-uniform base
// (HW adds lane*16); global src is per-lane (pre-swizzled there).
__device__ __forceinline__ void glds16(const ushort* g, ushort* l) {
  __builtin_amdgcn_global_load_lds(
      (const __attribute__((address_space(1))) void*)g,
      (__attribute__((address_space(3))) void*)l, 16, 0, 0);
}

// ---------------------------------------------------------------------------
// Fused prep: z<8  -> transpose+cast ctxt[b] (fp32 [C][N] -> bf16 [N][C])
//             z<16 -> transpose+cast x[b-8]
//             z=16 -> cast Wk/Wv to bf16 (first 128 blocks of the plane)
// ---------------------------------------------------------------------------
__global__ __launch_bounds__(256) void prep_kernel(
    const float* __restrict__ x, const float* __restrict__ ctxt,
    const float* __restrict__ Wk, const float* __restrict__ Wv,
    ushort* __restrict__ x_bf, ushort* __restrict__ ctxt_bf,
    ushort* __restrict__ wk_bf, ushort* __restrict__ wv_bf) {
  const int z = blockIdx.z;
  const int tid = threadIdx.x;
  if (z == 16) {
    const int id = blockIdx.y * 64 + blockIdx.x;
    if (id >= 128) return;
    const int t = (id * 256 + tid) * 4;   // HID*C = 131072 elems
    const float4 a = *(const float4*)(Wk + t);
    const float4 b = *(const float4*)(Wv + t);
    ushort4 ra, rb;
    ra.x = f2bf(a.x); ra.y = f2bf(a.y); ra.z = f2bf(a.z); ra.w = f2bf(a.w);
    rb.x = f2bf(b.x); rb.y = f2bf(b.y); rb.z = f2bf(b.z); rb.w = f2bf(b.w);
    *(ushort4*)(wk_bf + t) = ra;
    *(ushort4*)(wv_bf + t) = rb;
    return;
  }
  __shared__ float tile[64 * 65];
  const int b = z & 7;
  const float* src = (z < 8) ? ctxt : x;
  ushort* dst = (z < 8) ? ctxt_bf : x_bf;
  const int l0 = blockIdx.x * 64, r0 = blockIdx.y * 64;
  const int rr = tid >> 4, c4 = (tid & 15) << 2;
  const float* sp = src + ((size_t)b * C + r0) * N + l0;
#pragma unroll
  for (int p = 0; p < 4; ++p) {
    const float4 v = *(const float4*)(sp + (size_t)(rr + p * 16) * N + c4);
    float* tp = tile + (rr + p * 16) * 65 + c4;
    tp[0] = v.x; tp[1] = v.y; tp[2] = v.z; tp[3] = v.w;
  }
  __syncthreads();
  const int lr = tid >> 2, rb = (tid & 3) << 4;
  uint pk[8];
#pragma unroll
  for (int k = 0; k < 16; k += 2) {
    const uint lo = f2bf(tile[(rb + k) * 65 + lr]);
    const uint hi = f2bf(tile[(rb + k + 1) * 65 + lr]);
    pk[k >> 1] = lo | (hi << 16);
  }
  ushort* dp = dst + ((size_t)b * N + l0 + lr) * C + r0 + rb;
  *(uint4*)dp = *(uint4*)pk;
  *(uint4*)(dp + 8) = *(uint4*)(pk + 4);
}

// ---------------------------------------------------------------------------
// Kernel 1 (MFMA) -- R3 structure with R3 codegen (f2bf, 64 VGPR).
// Wave-per-d-slice, 32-m sub-tiles, glds double buffer for ctxt staging,
// single P/V buffer, 2 barriers/tile, in-loop weight loads (L1-resident).
// LDS 40 KB -> 4 blk/CU.
// ---------------------------------------------------------------------------
__global__ __launch_bounds__(256, 4) void kv_mfma_kernel(
    const ushort* __restrict__ ctxt_bf,   // [B][N][C] bf16
    const ushort* __restrict__ wk_bf,     // [HID][C]
    const ushort* __restrict__ wv_bf,
    float* __restrict__ ctx_part,         // [B*H][16][64*64]  ([d][e])
    float* __restrict__ z_part)           // [B*H][16][64]
{
  __shared__ __align__(16) ushort cb_s[2][32 * 256];  // 2 x 16 KB ctxt tiles
  __shared__ __align__(16) ushort p_s[64 * 32];       // 4 KB P ([d][m32])
  __shared__ __align__(16) ushort v_s[64 * 32];       // 4 KB V ([e][m32])
  const int mt = blockIdx.x, h = blockIdx.y, b = blockIdx.z;
  const int tid = threadIdx.x;
  const int w = tid >> 6, lane = tid & 63;
  const int col = lane & 15, quad = lane >> 4;
  const int dw = w * 16;
  const int swc = (col & 3) ^ ((col >> 2) & 3);   // P/V granule swizzle

  const ushort* wkp = wk_bf + (size_t)(h * 64 + dw + col) * C + quad * 8;
  const ushort* wvp = wv_bf + (size_t)(h * 64 + dw + col) * C + quad * 8;
  const ushort* cbase = ctxt_bf + ((size_t)b * N + (size_t)mt * 256) * C;

  const int grow0 = w * 8 + (lane >> 5);   // staging row (+ it*2)
  const int ggran = lane & 31;             // staging granule (16 B)

  const f32x4 z4 = {0.f, 0.f, 0.f, 0.f};
  f32x4 cacc[4];
#pragma unroll
  for (int j = 0; j < 4; ++j) cacc[j] = z4;
  float zl = 0.f;

  // prologue: stage sub-tile 0
#pragma unroll
  for (int it = 0; it < 4; ++it) {
    const int row = grow0 + it * 2;
    glds16(cbase + (size_t)row * C + ((ggran ^ (row & 7)) << 3),
           &cb_s[0][(w * 8 + it * 2) * 256]);
  }
  __syncthreads();

  for (int t = 0; t < 8; ++t) {
    const int cur = t & 1;
    if (t < 7) {
      const ushort* nb = cbase + (size_t)(t + 1) * 32 * C;
#pragma unroll
      for (int it = 0; it < 4; ++it) {
        const int row = grow0 + it * 2;
        glds16(nb + (size_t)row * C + ((ggran ^ (row & 7)) << 3),
               &cb_s[cur ^ 1][(w * 8 + it * 2) * 256]);
      }
    }

    // ---- K+V projection for own d-slice over 32 m (weights in-loop) ----
    f32x4 kacc[2], vacc[2];
#pragma unroll
    for (int i = 0; i < 2; ++i) { kacc[i] = z4; vacc[i] = z4; }
#pragma unroll
    for (int kk = 0; kk < 8; ++kk) {
      bf16x8 a[2];
#pragma unroll
      for (int i = 0; i < 2; ++i) {
        const int r = i * 16 + col;
        a[i] = *(const bf16x8*)(&cb_s[cur][r * 256 +
                  ((((kk << 2) + quad) ^ (r & 7)) << 3)]);
      }
      const bf16x8 wkf = *(const bf16x8*)(wkp + (size_t)kk * 32);
      const bf16x8 wvf = *(const bf16x8*)(wvp + (size_t)kk * 32);
#pragma unroll
      for (int i = 0; i < 2; ++i) {
        kacc[i] = mfma16(a[i], wkf, kacc[i]);
        vacc[i] = mfma16(a[i], wvf, vacc[i]);
      }
    }

    // ---- exp + stage P/V (own 16 d rows), Z partial ----
#pragma unroll
    for (int i = 0; i < 2; ++i) {
      const int off = (dw + col) * 32 +
                      (((i * 2 + (quad >> 1)) ^ swc) << 3) + ((quad & 1) << 2);
      const f32x4 k4 = kacc[i];
      const float e0 = __expf(k4[0]), e1 = __expf(k4[1]);
      const float e2 = __expf(k4[2]), e3 = __expf(k4[3]);
      zl += (e0 + e1) + (e2 + e3);
      ushort4 pk; pk.x = f2bf(e0); pk.y = f2bf(e1);
      pk.z = f2bf(e2); pk.w = f2bf(e3);
      *(ushort4*)(p_s + off) = pk;
      const f32x4 v4 = vacc[i];
      ushort4 vk; vk.x = f2bf(v4[0]); vk.y = f2bf(v4[1]);
      vk.z = f2bf(v4[2]); vk.w = f2bf(v4[3]);
      *(ushort4*)(v_s + off) = vk;
    }
    __syncthreads();

    // ---- PV accumulate: one K-step over this sub-tile's 32 m ----
    {
      const int g = (quad ^ swc) << 3;
      const bf16x8 pa = *(const bf16x8*)(p_s + (dw + col) * 32 + g);
      bf16x8 vb[4];
#pragma unroll
      for (int j = 0; j < 4; ++j)
        vb[j] = *(const bf16x8*)(v_s + (j * 16 + col) * 32 + g);
#pragma unroll
      for (int j = 0; j < 4; ++j) cacc[j] = mfma16(pa, vb[j], cacc[j]);
    }
    __syncthreads();   // P/V reuse + cb prefetch completion
  }

  // ---- Z: reduce over quads (wave owns its d-slice exclusively) ----
  {
    float s = zl;
    s += __shfl_xor(s, 16); s += __shfl_xor(s, 32);
    if (quad == 0)
      z_part[((size_t)(b * H + h) * 16 + mt) * 64 + dw + col] = s;
  }

  // ---- ctx epilogue: per-mt partials, [d][e] ----
  float* outp = ctx_part + ((size_t)(b * H + h) * 16 + mt) * 4096;
#pragma unroll
  for (int j = 0; j < 4; ++j)
#pragma unroll
    for (int r = 0; r < 4; ++r)
      outp[(size_t)(dw + quad * 4 + r) * 64 + j * 16 + col] = cacc[j][r];
}

// ---------------------------------------------------------------------------
// Kernel 2 (fused combine+a): A[b][h*64+e][c] =
//   sum_d (sum_p ctx_part[bh][p][d][e]) * SCALE/z[d] * Wq[h*64+d, c]
// Grid (B*H, 4).  The 16-way partial sum happens inline during the LDS fill
// (same p-order as the old combine -> bit-identical); ctx_part is L2/L3
// resident from kv.  Removes the combine launch + its HBM round-trip.
// ---------------------------------------------------------------------------
__global__ __launch_bounds__(256) void a_kernel(
    const float* __restrict__ ctx_part, const float* __restrict__ z_part,
    const float* __restrict__ Wq, float* __restrict__ A)   // [B][HID][C]
{
  const int bh = blockIdx.x, cti = blockIdx.y, tid = threadIdx.x;
  const int b = bh >> 3, h = bh & 7;
  const int c0 = cti << 6;
  __shared__ float ct[64 * 65];   // [e][d]
  __shared__ float wq[64 * 68];   // [d][c-tile]
  __shared__ float zs[64];
  if (tid < 64) {
    float z = 0.f;
#pragma unroll
    for (int p = 0; p < 16; ++p) z += z_part[((size_t)bh * 16 + p) * 64 + tid];
    zs[tid] = SCALE / z;
  }
  __syncthreads();
  const float* cp = ctx_part + (size_t)bh * 16 * 4096;
  for (int r = 0; r < 16; ++r) {
    const int idx = tid + (r << 8);
    float s = 0.f;
#pragma unroll
    for (int p = 0; p < 16; ++p) s += cp[(size_t)p * 4096 + idx];
    ct[(idx & 63) * 65 + (idx >> 6)] = s * zs[idx >> 6];
    wq[(idx >> 6) * 68 + (idx & 63)] =
        Wq[(size_t)(h * 64 + (idx >> 6)) * C + c0 + (idx & 63)];
  }
  __syncthreads();
  const int e = tid & 63, co = tid >> 6;
  float acc[16];
#pragma unroll
  for (int k = 0; k < 16; ++k) acc[k] = 0.f;
  for (int d = 0; d < 64; ++d) {
    const float cv = ct[e * 65 + d];
    const float* wr = wq + d * 68 + co * 16;
#pragma unroll
    for (int k = 0; k < 16; ++k) acc[k] += cv * wr[k];
  }
  float* Ar = A + ((size_t)b * HID + h * 64 + e) * C + c0 + co * 16;
#pragma unroll
  for (int k = 0; k < 16; ++k) Ar[k] = acc[k];
}

// ---------------------------------------------------------------------------
// Kernel 3: M[b] = Wo (256x512) @ A[b] (512x256) -> bf16 [b][o][c]
// 32x64 tiles, grid (32, B).  k-chunk 64, reg-staged write-late pipeline.
// ---------------------------------------------------------------------------
__global__ __launch_bounds__(256) void m_kernel(
    const float* __restrict__ A, const float* __restrict__ Wo,
    ushort* __restrict__ M_bf)
{
  const int tile = blockIdx.x, b = blockIdx.y;
  const int o0 = (tile & 7) << 5, c0 = (tile >> 3) << 6;
  const int tid = threadIdx.x, tx = tid & 15, ty = tid >> 4;
  __shared__ float wo_s[64 * 33];  // [k][o 32]
  __shared__ float a_s[64 * 68];   // [k][c 64]
  float acc[2][4] = {{0.f}};
  const int wo_o = tid >> 3, wo_k = (tid & 7) << 3;   // 8 k per thread
  const int a_k = tid >> 2, a_c = (tid & 3) << 4;     // 16 c per thread
  float4 wr0, wr1, ar0, ar1, ar2, ar3;
  {
    const float* wp = Wo + (size_t)(o0 + wo_o) * HID + wo_k;
    wr0 = *(const float4*)wp; wr1 = *(const float4*)(wp + 4);
    const float* ap = A + ((size_t)b * HID + a_k) * C + c0 + a_c;
    ar0 = *(const float4*)ap;       ar1 = *(const float4*)(ap + 4);
    ar2 = *(const float4*)(ap + 8); ar3 = *(const float4*)(ap + 12);
  }
  for (int t = 0; t < 8; ++t) {
    __syncthreads();   // previous compute done reading LDS
    {
      float* wd = wo_s + wo_k * 33 + wo_o;
      wd[0]   = wr0.x; wd[33]  = wr0.y; wd[66]  = wr0.z; wd[99]  = wr0.w;
      wd[132] = wr1.x; wd[165] = wr1.y; wd[198] = wr1.z; wd[231] = wr1.w;
      float* ad = a_s + a_k * 68 + a_c;
      *(float4*)ad = ar0;       *(float4*)(ad + 4) = ar1;
      *(float4*)(ad + 8) = ar2; *(float4*)(ad + 12) = ar3;
    }
    __syncthreads();
    if (t < 7) {
      const int k0 = (t + 1) << 6;
      const float* wp = Wo + (size_t)(o0 + wo_o) * HID + k0 + wo_k;
      wr0 = *(const float4*)wp; wr1 = *(const float4*)(wp + 4);
      const float* ap = A + ((size_t)b * HID + k0 + a_k) * C + c0 + a_c;
      ar0 = *(const float4*)ap;       ar1 = *(const float4*)(ap + 4);
      ar2 = *(const float4*)(ap + 8); ar3 = *(const float4*)(ap + 12);
    }
#pragma unroll
    for (int kc = 0; kc < 64; ++kc) {
      const float2 wv = *(const float2*)(wo_s + kc * 33 + ty * 2);
      const float4 av = *(const float4*)(a_s + kc * 68 + tx * 4);
      acc[0][0] += wv.x * av.x; acc[0][1] += wv.x * av.y;
      acc[0][2] += wv.x * av.z; acc[0][3] += wv.x * av.w;
      acc[1][0] += wv.y * av.x; acc[1][1] += wv.y * av.y;
      acc[1][2] += wv.y * av.z; acc[1][3] += wv.y * av.w;
    }
  }
#pragma unroll
  for (int i = 0; i < 2; ++i) {
    ushort4 r;
    r.x = f2bf(acc[i][0]); r.y = f2bf(acc[i][1]);
    r.z = f2bf(acc[i][2]); r.w = f2bf(acc[i][3]);
    *(ushort4*)(M_bf + ((size_t)b * C + o0 + ty * 2 + i) * C + c0 + tx * 4) = r;
  }
}

// ---------------------------------------------------------------------------
// Kernel 4 (MFMA): out[b] = M_b (256x256) @ X_b (256x4096) + bo
// Block->XCD remap: the 8 ot-blocks sharing one 128 KB x-tile get the same
// XCD and adjacent slots, so the x-tile stays in that XCD's L2.
// ---------------------------------------------------------------------------
__global__ __launch_bounds__(256, 4) void out_mfma_kernel(
    const ushort* __restrict__ M_bf,     // [B][C][C] bf16
    const ushort* __restrict__ x_bf,     // [B][N][C] bf16
    const float* __restrict__ bo, float* __restrict__ out)
{
  const int r = blockIdx.x + 16 * blockIdx.y + 128 * blockIdx.z;  // 0..1023
  const int xcd = r & 7, slot = r >> 3;
  const int grp = xcd * 16 + (slot >> 3);   // 0..127 = (b, nt)
  const int ot = slot & 7;
  const int b = grp >> 4, nt = grp & 15;
  const int tid = threadIdx.x;
  const int w = tid >> 6, lane = tid & 63;
  const int col = lane & 15, quad = lane >> 4;
  const int o0 = ot * 32;
  const size_t n_base = (size_t)nt * 256 + w * 64;
  const ushort* Ab = M_bf + ((size_t)b * C + o0 + col) * C + quad * 8;
  const ushort* Bb = x_bf + ((size_t)b * N + n_base) * C + quad * 8;

  const f32x4 z4 = {0.f, 0.f, 0.f, 0.f};
  f32x4 acc[2][4];
#pragma unroll
  for (int i = 0; i < 2; ++i)
#pragma unroll
    for (int j = 0; j < 4; ++j) acc[i][j] = z4;

#pragma unroll
  for (int kk = 0; kk < 8; ++kk) {
    bf16x8 af[2], bfz[4];
#pragma unroll
    for (int i = 0; i < 2; ++i)
      af[i] = *(const bf16x8*)(Ab + (size_t)(i * 16) * C + kk * 32);
#pragma unroll
    for (int j = 0; j < 4; ++j)
      bfz[j] = *(const bf16x8*)(Bb + (size_t)(j * 16 + col) * C + kk * 32);
#pragma unroll
    for (int i = 0; i < 2; ++i)
#pragma unroll
      for (int j = 0; j < 4; ++j) acc[i][j] = mfma16(af[i], bfz[j], acc[i][j]);
  }

#pragma unroll
  for (int i = 0; i < 2; ++i)
#pragma unroll
    for (int r2 = 0; r2 < 4; ++r2) {
      const int o = o0 + i * 16 + quad * 4 + r2;
      const float bias = bo[o];
      float* op = out + ((size_t)b * C + o) * N + n_base + col;
#pragma unroll
      for (int j = 0; j < 4; ++j) op[j * 16] = acc[i][j][r2] + bias;
    }
}

// ---------------------------------------------------------------------------
extern "C" void kernel_launch(void* const* d_in, const int* in_sizes, int n_in,
                              void* d_out, int out_size, void* d_ws, size_t ws_size,
                              hipStream_t stream) {
  const float* x    = (const float*)d_in[0];
  const float* ctxt = (const float*)d_in[1];
  const float* Wq   = (const float*)d_in[2];
  const float* Wk   = (const float*)d_in[3];
  const float* Wv   = (const float*)d_in[4];
  const float* Wo   = (const float*)d_in[5];
  const float* bo   = (const float*)d_in[6];
  float* out = (float*)d_out;

  char* p = (char*)d_ws;
  ushort* ctxt_bf = (ushort*)p;  p += (size_t)B * N * C * 2;        // 16 MB
  ushort* x_bf    = (ushort*)p;  p += (size_t)B * N * C * 2;        // 16 MB
  ushort* wk_bf   = (ushort*)p;  p += (size_t)HID * C * 2;
  ushort* wv_bf   = (ushort*)p;  p += (size_t)HID * C * 2;
  ushort* M_bf    = (ushort*)p;  p += (size_t)B * C * C * 2;
  float*  z_part  = (float*)p;   p += (size_t)B * H * 16 * 64 * 4;
  float*  A       = (float*)p;   p += (size_t)B * HID * C * 4;      // 4 MB
  float*  ctx_part= (float*)p;   p += (size_t)B * H * 16 * 4096 * 4; // 16.8 MB

  prep_kernel<<<dim3(N / 64, C / 64, 17), 256, 0, stream>>>(
      x, ctxt, Wk, Wv, x_bf, ctxt_bf, wk_bf, wv_bf);
  kv_mfma_kernel<<<dim3(16, H, B), 256, 0, stream>>>(
      ctxt_bf, wk_bf, wv_bf, ctx_part, z_part);
  a_kernel<<<dim3(B * H, 4), 256, 0, stream>>>(ctx_part, z_part, Wq, A);
  m_kernel<<<dim3(32, B), 256, 0, stream>>>(A, Wo, M_bf);
  out_mfma_kernel<<<dim3(N / 256, C / 32, B), 256, 0, stream>>>(M_bf, x_bf, bo, out);
}

// Round 9
// 190.836 us; speedup vs baseline: 1.2954x; 1.0592x over previous
//
#include <hip/hip_runtime.h>

#define B   8
#define C   256
#define N   4096
#define H   8
#define D   64
#define HID 512
#define SCALE 0.125f

typedef __attribute__((ext_vector_type(8))) __bf16 bf16x8;
typedef __attribute__((ext_vector_type(4))) float f32x4;

// Software RNE fp32->bf16.  Bit-identical to v_cvt for normals, but the
// integer sequence keeps kv's register allocation at 64 VGPR -- the hw-cast
// variant (R7) dropped it to 52 and the shrunken ILP window cost 1.7x.
__device__ __forceinline__ ushort f2bf(float f) {
  union { float f; unsigned u; } v; v.f = f;
  unsigned r = v.u + 0x7FFFu + ((v.u >> 16) & 1u);
  return (ushort)(r >> 16);
}

__device__ __forceinline__ f32x4 mfma16(bf16x8 a, bf16x8 b, f32x4 c) {
  return __builtin_amdgcn_mfma_f32_16x16x32_bf16(a, b, c, 0, 0, 0);
}

// global -> LDS direct DMA, 16 B per lane.  LDS dest is wave-uniform base
// (HW adds lane*16); global src is per-lane (pre-swizzled there).
__device__ __forceinline__ void glds16(const ushort* g, ushort* l) {
  __builtin_amdgcn_global_load_lds(
      (const __attribute__((address_space(1))) void*)g,
      (__attribute__((address_space(3))) void*)l, 16, 0, 0);
}

// ---------------------------------------------------------------------------
// Fused prep: z<8  -> transpose+cast ctxt[b] (fp32 [C][N] -> bf16 [N][C])
//             z<16 -> transpose+cast x[b-8]
//             z=16 -> cast Wk/Wv to bf16 (first 128 blocks of the plane)
// ---------------------------------------------------------------------------
__global__ __launch_bounds__(256) void prep_kernel(
    const float* __restrict__ x, const float* __restrict__ ctxt,
    const float* __restrict__ Wk, const float* __restrict__ Wv,
    ushort* __restrict__ x_bf, ushort* __restrict__ ctxt_bf,
    ushort* __restrict__ wk_bf, ushort* __restrict__ wv_bf) {
  const int z = blockIdx.z;
  const int tid = threadIdx.x;
  if (z == 16) {
    const int id = blockIdx.y * 64 + blockIdx.x;
    if (id >= 128) return;
    const int t = (id * 256 + tid) * 4;   // HID*C = 131072 elems
    const float4 a = *(const float4*)(Wk + t);
    const float4 b = *(const float4*)(Wv + t);
    ushort4 ra, rb;
    ra.x = f2bf(a.x); ra.y = f2bf(a.y); ra.z = f2bf(a.z); ra.w = f2bf(a.w);
    rb.x = f2bf(b.x); rb.y = f2bf(b.y); rb.z = f2bf(b.z); rb.w = f2bf(b.w);
    *(ushort4*)(wk_bf + t) = ra;
    *(ushort4*)(wv_bf + t) = rb;
    return;
  }
  __shared__ float tile[64 * 65];
  const int b = z & 7;
  const float* src = (z < 8) ? ctxt : x;
  ushort* dst = (z < 8) ? ctxt_bf : x_bf;
  const int l0 = blockIdx.x * 64, r0 = blockIdx.y * 64;
  const int rr = tid >> 4, c4 = (tid & 15) << 2;
  const float* sp = src + ((size_t)b * C + r0) * N + l0;
#pragma unroll
  for (int p = 0; p < 4; ++p) {
    const float4 v = *(const float4*)(sp + (size_t)(rr + p * 16) * N + c4);
    float* tp = tile + (rr + p * 16) * 65 + c4;
    tp[0] = v.x; tp[1] = v.y; tp[2] = v.z; tp[3] = v.w;
  }
  __syncthreads();
  const int lr = tid >> 2, rb = (tid & 3) << 4;
  uint pk[8];
#pragma unroll
  for (int k = 0; k < 16; k += 2) {
    const uint lo = f2bf(tile[(rb + k) * 65 + lr]);
    const uint hi = f2bf(tile[(rb + k + 1) * 65 + lr]);
    pk[k >> 1] = lo | (hi << 16);
  }
  ushort* dp = dst + ((size_t)b * N + l0 + lr) * C + r0 + rb;
  *(uint4*)dp = *(uint4*)pk;
  *(uint4*)(dp + 8) = *(uint4*)(pk + 4);
}

// ---------------------------------------------------------------------------
// Kernel 1 (MFMA) -- R3 structure with R3 codegen (f2bf, 64 VGPR).
// Wave-per-d-slice, 32-m sub-tiles, glds double buffer for ctxt staging,
// single P/V buffer, 2 barriers/tile, in-loop weight loads (L1-resident).
// LDS 40 KB -> 4 blk/CU.
// ---------------------------------------------------------------------------
__global__ __launch_bounds__(256, 4) void kv_mfma_kernel(
    const ushort* __restrict__ ctxt_bf,   // [B][N][C] bf16
    const ushort* __restrict__ wk_bf,     // [HID][C]
    const ushort* __restrict__ wv_bf,
    float* __restrict__ ctx_part,         // [B*H][16][64*64]  ([d][e])
    float* __restrict__ z_part)           // [B*H][16][64]
{
  __shared__ __align__(16) ushort cb_s[2][32 * 256];  // 2 x 16 KB ctxt tiles
  __shared__ __align__(16) ushort p_s[64 * 32];       // 4 KB P ([d][m32])
  __shared__ __align__(16) ushort v_s[64 * 32];       // 4 KB V ([e][m32])
  const int mt = blockIdx.x, h = blockIdx.y, b = blockIdx.z;
  const int tid = threadIdx.x;
  const int w = tid >> 6, lane = tid & 63;
  const int col = lane & 15, quad = lane >> 4;
  const int dw = w * 16;
  const int swc = (col & 3) ^ ((col >> 2) & 3);   // P/V granule swizzle

  const ushort* wkp = wk_bf + (size_t)(h * 64 + dw + col) * C + quad * 8;
  const ushort* wvp = wv_bf + (size_t)(h * 64 + dw + col) * C + quad * 8;
  const ushort* cbase = ctxt_bf + ((size_t)b * N + (size_t)mt * 256) * C;

  const int grow0 = w * 8 + (lane >> 5);   // staging row (+ it*2)
  const int ggran = lane & 31;             // staging granule (16 B)

  const f32x4 z4 = {0.f, 0.f, 0.f, 0.f};
  f32x4 cacc[4];
#pragma unroll
  for (int j = 0; j < 4; ++j) cacc[j] = z4;
  float zl = 0.f;

  // prologue: stage sub-tile 0
#pragma unroll
  for (int it = 0; it < 4; ++it) {
    const int row = grow0 + it * 2;
    glds16(cbase + (size_t)row * C + ((ggran ^ (row & 7)) << 3),
           &cb_s[0][(w * 8 + it * 2) * 256]);
  }
  __syncthreads();

  for (int t = 0; t < 8; ++t) {
    const int cur = t & 1;
    if (t < 7) {
      const ushort* nb = cbase + (size_t)(t + 1) * 32 * C;
#pragma unroll
      for (int it = 0; it < 4; ++it) {
        const int row = grow0 + it * 2;
        glds16(nb + (size_t)row * C + ((ggran ^ (row & 7)) << 3),
               &cb_s[cur ^ 1][(w * 8 + it * 2) * 256]);
      }
    }

    // ---- K+V projection for own d-slice over 32 m (weights in-loop) ----
    f32x4 kacc[2], vacc[2];
#pragma unroll
    for (int i = 0; i < 2; ++i) { kacc[i] = z4; vacc[i] = z4; }
#pragma unroll
    for (int kk = 0; kk < 8; ++kk) {
      bf16x8 a[2];
#pragma unroll
      for (int i = 0; i < 2; ++i) {
        const int r = i * 16 + col;
        a[i] = *(const bf16x8*)(&cb_s[cur][r * 256 +
                  ((((kk << 2) + quad) ^ (r & 7)) << 3)]);
      }
      const bf16x8 wkf = *(const bf16x8*)(wkp + (size_t)kk * 32);
      const bf16x8 wvf = *(const bf16x8*)(wvp + (size_t)kk * 32);
#pragma unroll
      for (int i = 0; i < 2; ++i) {
        kacc[i] = mfma16(a[i], wkf, kacc[i]);
        vacc[i] = mfma16(a[i], wvf, vacc[i]);
      }
    }

    // ---- exp + stage P/V (own 16 d rows), Z partial ----
#pragma unroll
    for (int i = 0; i < 2; ++i) {
      const int off = (dw + col) * 32 +
                      (((i * 2 + (quad >> 1)) ^ swc) << 3) + ((quad & 1) << 2);
      const f32x4 k4 = kacc[i];
      const float e0 = __expf(k4[0]), e1 = __expf(k4[1]);
      const float e2 = __expf(k4[2]), e3 = __expf(k4[3]);
      zl += (e0 + e1) + (e2 + e3);
      ushort4 pk; pk.x = f2bf(e0); pk.y = f2bf(e1);
      pk.z = f2bf(e2); pk.w = f2bf(e3);
      *(ushort4*)(p_s + off) = pk;
      const f32x4 v4 = vacc[i];
      ushort4 vk; vk.x = f2bf(v4[0]); vk.y = f2bf(v4[1]);
      vk.z = f2bf(v4[2]); vk.w = f2bf(v4[3]);
      *(ushort4*)(v_s + off) = vk;
    }
    __syncthreads();

    // ---- PV accumulate: one K-step over this sub-tile's 32 m ----
    {
      const int g = (quad ^ swc) << 3;
      const bf16x8 pa = *(const bf16x8*)(p_s + (dw + col) * 32 + g);
      bf16x8 vb[4];
#pragma unroll
      for (int j = 0; j < 4; ++j)
        vb[j] = *(const bf16x8*)(v_s + (j * 16 + col) * 32 + g);
#pragma unroll
      for (int j = 0; j < 4; ++j) cacc[j] = mfma16(pa, vb[j], cacc[j]);
    }
    __syncthreads();   // P/V reuse + cb prefetch completion
  }

  // ---- Z: reduce over quads (wave owns its d-slice exclusively) ----
  {
    float s = zl;
    s += __shfl_xor(s, 16); s += __shfl_xor(s, 32);
    if (quad == 0)
      z_part[((size_t)(b * H + h) * 16 + mt) * 64 + dw + col] = s;
  }

  // ---- ctx epilogue: per-mt partials, [d][e] ----
  float* outp = ctx_part + ((size_t)(b * H + h) * 16 + mt) * 4096;
#pragma unroll
  for (int j = 0; j < 4; ++j)
#pragma unroll
    for (int r = 0; r < 4; ++r)
      outp[(size_t)(dw + quad * 4 + r) * 64 + j * 16 + col] = cacc[j][r];
}

// ---------------------------------------------------------------------------
// Kernel 2 (fused combine+a): A[b][h*64+e][c] =
//   sum_d (sum_p ctx_part[bh][p][d][e]) * SCALE/z[d] * Wq[h*64+d, c]
// Grid (B*H, 4).  16-way partial sum inline during LDS fill (bit-identical
// p-order); ctx_part is L2/L3 resident from kv.
// ---------------------------------------------------------------------------
__global__ __launch_bounds__(256) void a_kernel(
    const float* __restrict__ ctx_part, const float* __restrict__ z_part,
    const float* __restrict__ Wq, float* __restrict__ A)   // [B][HID][C]
{
  const int bh = blockIdx.x, cti = blockIdx.y, tid = threadIdx.x;
  const int b = bh >> 3, h = bh & 7;
  const int c0 = cti << 6;
  __shared__ float ct[64 * 65];   // [e][d]
  __shared__ float wq[64 * 68];   // [d][c-tile]
  __shared__ float zs[64];
  if (tid < 64) {
    float z = 0.f;
#pragma unroll
    for (int p = 0; p < 16; ++p) z += z_part[((size_t)bh * 16 + p) * 64 + tid];
    zs[tid] = SCALE / z;
  }
  __syncthreads();
  const float* cp = ctx_part + (size_t)bh * 16 * 4096;
  for (int r = 0; r < 16; ++r) {
    const int idx = tid + (r << 8);
    float s = 0.f;
#pragma unroll
    for (int p = 0; p < 16; ++p) s += cp[(size_t)p * 4096 + idx];
    ct[(idx & 63) * 65 + (idx >> 6)] = s * zs[idx >> 6];
    wq[(idx >> 6) * 68 + (idx & 63)] =
        Wq[(size_t)(h * 64 + (idx >> 6)) * C + c0 + (idx & 63)];
  }
  __syncthreads();
  const int e = tid & 63, co = tid >> 6;
  float acc[16];
#pragma unroll
  for (int k = 0; k < 16; ++k) acc[k] = 0.f;
  for (int d = 0; d < 64; ++d) {
    const float cv = ct[e * 65 + d];
    const float* wr = wq + d * 68 + co * 16;
#pragma unroll
    for (int k = 0; k < 16; ++k) acc[k] += cv * wr[k];
  }
  float* Ar = A + ((size_t)b * HID + h * 64 + e) * C + c0 + co * 16;
#pragma unroll
  for (int k = 0; k < 16; ++k) Ar[k] = acc[k];
}

// ---------------------------------------------------------------------------
// Kernel 3: M[b] = Wo (256x512) @ A[b] (512x256) -> bf16 [b][o][c]
// 32x64 tiles, grid (32, B).  k-chunk 64, reg-staged write-late pipeline.
// ---------------------------------------------------------------------------
__global__ __launch_bounds__(256) void m_kernel(
    const float* __restrict__ A, const float* __restrict__ Wo,
    ushort* __restrict__ M_bf)
{
  const int tile = blockIdx.x, b = blockIdx.y;
  const int o0 = (tile & 7) << 5, c0 = (tile >> 3) << 6;
  const int tid = threadIdx.x, tx = tid & 15, ty = tid >> 4;
  __shared__ float wo_s[64 * 33];  // [k][o 32]
  __shared__ float a_s[64 * 68];   // [k][c 64]
  float acc[2][4] = {{0.f}};
  const int wo_o = tid >> 3, wo_k = (tid & 7) << 3;   // 8 k per thread
  const int a_k = tid >> 2, a_c = (tid & 3) << 4;     // 16 c per thread
  float4 wr0, wr1, ar0, ar1, ar2, ar3;
  {
    const float* wp = Wo + (size_t)(o0 + wo_o) * HID + wo_k;
    wr0 = *(const float4*)wp; wr1 = *(const float4*)(wp + 4);
    const float* ap = A + ((size_t)b * HID + a_k) * C + c0 + a_c;
    ar0 = *(const float4*)ap;       ar1 = *(const float4*)(ap + 4);
    ar2 = *(const float4*)(ap + 8); ar3 = *(const float4*)(ap + 12);
  }
  for (int t = 0; t < 8; ++t) {
    __syncthreads();   // previous compute done reading LDS
    {
      float* wd = wo_s + wo_k * 33 + wo_o;
      wd[0]   = wr0.x; wd[33]  = wr0.y; wd[66]  = wr0.z; wd[99]  = wr0.w;
      wd[132] = wr1.x; wd[165] = wr1.y; wd[198] = wr1.z; wd[231] = wr1.w;
      float* ad = a_s + a_k * 68 + a_c;
      *(float4*)ad = ar0;       *(float4*)(ad + 4) = ar1;
      *(float4*)(ad + 8) = ar2; *(float4*)(ad + 12) = ar3;
    }
    __syncthreads();
    if (t < 7) {
      const int k0 = (t + 1) << 6;
      const float* wp = Wo + (size_t)(o0 + wo_o) * HID + k0 + wo_k;
      wr0 = *(const float4*)wp; wr1 = *(const float4*)(wp + 4);
      const float* ap = A + ((size_t)b * HID + k0 + a_k) * C + c0 + a_c;
      ar0 = *(const float4*)ap;       ar1 = *(const float4*)(ap + 4);
      ar2 = *(const float4*)(ap + 8); ar3 = *(const float4*)(ap + 12);
    }
#pragma unroll
    for (int kc = 0; kc < 64; ++kc) {
      const float2 wv = *(const float2*)(wo_s + kc * 33 + ty * 2);
      const float4 av = *(const float4*)(a_s + kc * 68 + tx * 4);
      acc[0][0] += wv.x * av.x; acc[0][1] += wv.x * av.y;
      acc[0][2] += wv.x * av.z; acc[0][3] += wv.x * av.w;
      acc[1][0] += wv.y * av.x; acc[1][1] += wv.y * av.y;
      acc[1][2] += wv.y * av.z; acc[1][3] += wv.y * av.w;
    }
  }
#pragma unroll
  for (int i = 0; i < 2; ++i) {
    ushort4 r;
    r.x = f2bf(acc[i][0]); r.y = f2bf(acc[i][1]);
    r.z = f2bf(acc[i][2]); r.w = f2bf(acc[i][3]);
    *(ushort4*)(M_bf + ((size_t)b * C + o0 + ty * 2 + i) * C + c0 + tx * 4) = r;
  }
}

// ---------------------------------------------------------------------------
// Kernel 4 (MFMA): out[b] = M_b (256x256) @ X_b (256x4096) + bo
// Rebuilt on the proven kv skeleton: glds double-buffered x staging (same
// swizzle), 32-n sub-tiles, 1 barrier/sub-tile, M fragments hoisted to
// registers (64 VGPR; ~115 total < 170 cap -- spill-safe).  Grid
// (32 nt, 2 ot, 8 b) = 512 blocks; wave owns a 32-o slice.  Replaces the
// direct-global-load MFMA loop that was latency-bound every kk.
// ---------------------------------------------------------------------------
__global__ __launch_bounds__(256, 3) void out_mfma_kernel(
    const ushort* __restrict__ M_bf,     // [B][C][C] bf16
    const ushort* __restrict__ x_bf,     // [B][N][C] bf16
    const float* __restrict__ bo, float* __restrict__ out)
{
  __shared__ __align__(16) ushort xs[2][32 * 256];   // 2 x 16 KB x tiles
  const int nt = blockIdx.x;           // n base nt*128
  const int ot = blockIdx.y;           // o base ot*128
  const int b  = blockIdx.z;
  const int tid = threadIdx.x;
  const int w = tid >> 6, lane = tid & 63;
  const int col = lane & 15, quad = lane >> 4;
  const int ow = ot * 128 + w * 32;    // wave's 32-o slice

  const ushort* xbase = x_bf + ((size_t)b * N + (size_t)nt * 128) * C;
  const int grow0 = w * 8 + (lane >> 5);   // staging row (+ it*2)
  const int ggran = lane & 31;             // staging granule (16 B)

  // hoist M fragments (sub-tile invariant): 8 kk x 2 o-frags = 64 VGPR
  bf16x8 mf[8][2];
#pragma unroll
  for (int kk = 0; kk < 8; ++kk)
#pragma unroll
    for (int i = 0; i < 2; ++i)
      mf[kk][i] = *(const bf16x8*)(M_bf +
          ((size_t)b * C + ow + i * 16 + col) * C + kk * 32 + quad * 8);

  // hoist bias for this lane's 8 output rows
  float bias[2][4];
#pragma unroll
  for (int i = 0; i < 2; ++i)
#pragma unroll
    for (int r = 0; r < 4; ++r)
      bias[i][r] = bo[ow + i * 16 + quad * 4 + r];

  // prologue: stage sub-tile 0
#pragma unroll
  for (int it = 0; it < 4; ++it) {
    const int row = grow0 + it * 2;
    glds16(xbase + (size_t)row * C + ((ggran ^ (row & 7)) << 3),
           &xs[0][(w * 8 + it * 2) * 256]);
  }
  __syncthreads();

  for (int t = 0; t < 4; ++t) {
    const int cur = t & 1;
    if (t < 3) {
      const ushort* nb = xbase + (size_t)(t + 1) * 32 * C;
#pragma unroll
      for (int it = 0; it < 4; ++it) {
        const int row = grow0 + it * 2;
        glds16(nb + (size_t)row * C + ((ggran ^ (row & 7)) << 3),
               &xs[cur ^ 1][(w * 8 + it * 2) * 256]);
      }
    }

    const f32x4 z4 = {0.f, 0.f, 0.f, 0.f};
    f32x4 acc[2][2];
#pragma unroll
    for (int i = 0; i < 2; ++i)
#pragma unroll
      for (int j = 0; j < 2; ++j) acc[i][j] = z4;

#pragma unroll
    for (int kk = 0; kk < 8; ++kk) {
      bf16x8 bx[2];
#pragma unroll
      for (int j = 0; j < 2; ++j) {
        const int r = j * 16 + col;
        bx[j] = *(const bf16x8*)(&xs[cur][r * 256 +
                  ((((kk << 2) + quad) ^ (r & 7)) << 3)]);
      }
#pragma unroll
      for (int i = 0; i < 2; ++i)
#pragma unroll
        for (int j = 0; j < 2; ++j)
          acc[i][j] = mfma16(mf[kk][i], bx[j], acc[i][j]);
    }

    // store D[o][n]: o = ow+i*16+quad*4+r, n = nt*128 + t*32 + j*16 + col
#pragma unroll
    for (int i = 0; i < 2; ++i)
#pragma unroll
      for (int r = 0; r < 4; ++r) {
        const int o = ow + i * 16 + quad * 4 + r;
        float* op = out + ((size_t)b * C + o) * N + nt * 128 + t * 32 + col;
#pragma unroll
        for (int j = 0; j < 2; ++j)
          op[j * 16] = acc[i][j][r] + bias[i][r];
      }
    __syncthreads();   // glds (t+1) drain + xs[cur] reuse protection
  }
}

// ---------------------------------------------------------------------------
extern "C" void kernel_launch(void* const* d_in, const int* in_sizes, int n_in,
                              void* d_out, int out_size, void* d_ws, size_t ws_size,
                              hipStream_t stream) {
  const float* x    = (const float*)d_in[0];
  const float* ctxt = (const float*)d_in[1];
  const float* Wq   = (const float*)d_in[2];
  const float* Wk   = (const float*)d_in[3];
  const float* Wv   = (const float*)d_in[4];
  const float* Wo   = (const float*)d_in[5];
  const float* bo   = (const float*)d_in[6];
  float* out = (float*)d_out;

  char* p = (char*)d_ws;
  ushort* ctxt_bf = (ushort*)p;  p += (size_t)B * N * C * 2;        // 16 MB
  ushort* x_bf    = (ushort*)p;  p += (size_t)B * N * C * 2;        // 16 MB
  ushort* wk_bf   = (ushort*)p;  p += (size_t)HID * C * 2;
  ushort* wv_bf   = (ushort*)p;  p += (size_t)HID * C * 2;
  ushort* M_bf    = (ushort*)p;  p += (size_t)B * C * C * 2;
  float*  z_part  = (float*)p;   p += (size_t)B * H * 16 * 64 * 4;
  float*  A       = (float*)p;   p += (size_t)B * HID * C * 4;      // 4 MB
  float*  ctx_part= (float*)p;   p += (size_t)B * H * 16 * 4096 * 4; // 16.8 MB

  prep_kernel<<<dim3(N / 64, C / 64, 17), 256, 0, stream>>>(
      x, ctxt, Wk, Wv, x_bf, ctxt_bf, wk_bf, wv_bf);
  kv_mfma_kernel<<<dim3(16, H, B), 256, 0, stream>>>(
      ctxt_bf, wk_bf, wv_bf, ctx_part, z_part);
  a_kernel<<<dim3(B * H, 4), 256, 0, stream>>>(ctx_part, z_part, Wq, A);
  m_kernel<<<dim3(32, B), 256, 0, stream>>>(A, Wo, M_bf);
  out_mfma_kernel<<<dim3(32, 2, B), 256, 0, stream>>>(M_bf, x_bf, bo, out);
}